// Round 4
// baseline (1892.194 us; speedup 1.0000x reference)
//
#include <hip/hip_runtime.h>
#include <stdint.h>

// Problem sizes (fixed by reference)
#define NB   64
#define NIN  512
#define NHID 1024
#define NOUT 512
#define NT   1024

#define LSTRIDE 128   // u16 entries per (b,t) list, sentinel-padded to FULL length
#define P1 64         // fc1 tile dword pitch
#define P2 32         // fc2 tile dword pitch

// Loihi CUBA constants (exact in fp32)
#define A_I   0.75f
#define A_V   0.96875f
#define WSC   64.0f
#define THETA 5120.0f

// Keep a loaded value in a VGPR at this program point: prevents the compiler
// from sinking the load to its use site or scalarizing it to s_load (SMEM
// shares lgkmcnt with LDS and completes out-of-order -> forces lgkmcnt(0)
// drains that destroy the ds_read pipeline).
#define PIN4(U) asm volatile("" : "+v"((U).x), "+v"((U).y), "+v"((U).z), "+v"((U).w))
#define PIN1(U) asm volatile("" : "+v"(U))

// ---------------------------------------------------------------------------
// K1: binarize x (B,Nin,T) fp32 -> bitmask bits1[b][t][iw] (u32), coalesced.
// ---------------------------------------------------------------------------
__global__ void __launch_bounds__(256) k_bits1(const float* __restrict__ x,
                                               uint32_t* __restrict__ bits1) {
  int blk = blockIdx.x;          // b*64 + iw*4 + tc
  int b  = blk >> 6;
  int iw = (blk >> 2) & 15;
  int tc = blk & 3;
  int t  = tc * 256 + threadIdx.x;
  const float* xp = x + ((size_t)(b * NIN + iw * 32)) * NT + t;
  uint32_t w = 0;
#pragma unroll
  for (int j = 0; j < 32; ++j) {
    float v = xp[(size_t)j * NT];
    if (v > 0.5f) w |= (1u << j);
  }
  bits1[((size_t)b * NT + t) * 16 + iw] = w;
}

// ---------------------------------------------------------------------------
// Extract per-(b,t) ascending index lists, PRE-SCALED by <<shift (so the
// consumer's LDS dword index is just val + lane). cnt stores the GROUP count
// ceil(c/16). Full LSTRIDE sentinel-padded (sentinel_scaled maps to the
// zeroed LDS row; +0.0f adds are bit-neutral).
// ---------------------------------------------------------------------------
__global__ void __launch_bounds__(256) k_extract(const uint64_t* __restrict__ bits,
                                                 uint32_t* __restrict__ cnt,
                                                 uint16_t* __restrict__ list,
                                                 int words, int sentinel_scaled,
                                                 int shift) {
  int gid = blockIdx.x * 256 + threadIdx.x;   // = b*NT + t
  const uint64_t* wp = bits + (size_t)gid * words;
  uint16_t* lp = list + (size_t)gid * LSTRIDE;
  int c = 0;
  for (int w = 0; w < words; ++w) {
    uint64_t v = wp[w];
    while (v) {
      int j = __builtin_ctzll(v);
      v &= v - 1;
      if (c < LSTRIDE) lp[c] = (uint16_t)(((w << 6) + j) << shift);
      ++c;
    }
  }
  if (c > LSTRIDE) c = LSTRIDE;
  cnt[gid] = (uint32_t)((c + 15) >> 4);       // group count
  int cp = c;
  if (cp & 1) { lp[cp] = (uint16_t)sentinel_scaled; ++cp; }
  uint32_t s2 = (uint32_t)sentinel_scaled * 0x10001u;
  uint32_t* lp32 = (uint32_t*)lp;
  for (int k = cp >> 1; k < LSTRIDE / 2; ++k) lp32[k] = s2;
}

// Sequential single-accumulator sums: order = ascending list entries,
// bit-identical to the validated round-1/round-3 kernels.
#define SUM16(ACC, B) do { _Pragma("unroll") \
  for (int q_ = 0; q_ < 16; ++q_) (ACC) += (B)[q_]; } while (0)
#define SUM8(ACC, B) do { _Pragma("unroll") \
  for (int q_ = 0; q_ < 8; ++q_) (ACC) += (B)[q_]; } while (0)

// ---------------------------------------------------------------------------
// K2: fused fc1 + LIF -> spike bitmask bits2[b][t][hq] (u64).
// XCD-swizzled blocks: the 16 hq-blocks sharing one bq (4 batches' lists,
// ~1MB + w1 2MB) land on one XCD's L2. 4 waves = 4 batches, 64 lanes = 64
// hidden. Next-t list prefetched into 12 pinned uint4 (96 entries; JIT
// fallback beyond); 16-entry ping-pong LDS pipeline carried ACROSS t
// boundaries (group 0 of t+1 issued before t's LIF).
// ---------------------------------------------------------------------------
__global__ void __launch_bounds__(256, 1) k_fc1(const float* __restrict__ w1,
                                                const uint32_t* __restrict__ cnt1,
                                                const uint16_t* __restrict__ list1,
                                                uint64_t* __restrict__ bits2) {
  extern __shared__ float lds[];   // (NIN+1) x 64
  int xcd = blockIdx.x & 7, slot = blockIdx.x >> 3;
  int bq = (xcd << 1) | (slot & 1);
  int hq = slot >> 1;
  int h0 = hq * 64;
  for (int idx = threadIdx.x; idx < NIN * 64; idx += 256) {
    int hl = idx >> 9;             // 0..63
    int i  = idx & (NIN - 1);
    lds[i * P1 + hl] = w1[(size_t)(h0 + hl) * NIN + i];
  }
  if (threadIdx.x < 64) lds[NIN * P1 + threadIdx.x] = 0.0f;  // sentinel row
  __syncthreads();

  int wid = threadIdx.x >> 6, lane = threadIdx.x & 63;
  int b = bq * 4 + wid;
  size_t bt = (size_t)b * NT;
  const uint4* Lbase = (const uint4*)list1;   // chunk kc of (b,t) at [(b*NT+t)*16 + kc]
  float cur = 0.f, vol = 0.f;
  float bf0[16], bf1[16];

  uint4 ct[12], rt[12];
  int cntC;
  {
    uint32_t cw = cnt1[bt];
    PIN1(cw);
    const uint4* Lp = Lbase + bt * 16;
#pragma unroll
    for (int k = 0; k < 12; ++k) ct[k] = Lp[k];
#pragma unroll
    for (int k = 0; k < 12; ++k) PIN4(ct[k]);
    cntC = (int)cw;
  }

#define FC1_LOADG(BUF, CA, CB) do {                                             \
    uint4 ca_ = (CA), cb_ = (CB);                                               \
    BUF[0]  = lds[(ca_.x & 0xffffu) + lane];                                    \
    BUF[1]  = lds[(ca_.x >> 16)     + lane];                                    \
    BUF[2]  = lds[(ca_.y & 0xffffu) + lane];                                    \
    BUF[3]  = lds[(ca_.y >> 16)     + lane];                                    \
    BUF[4]  = lds[(ca_.z & 0xffffu) + lane];                                    \
    BUF[5]  = lds[(ca_.z >> 16)     + lane];                                    \
    BUF[6]  = lds[(ca_.w & 0xffffu) + lane];                                    \
    BUF[7]  = lds[(ca_.w >> 16)     + lane];                                    \
    BUF[8]  = lds[(cb_.x & 0xffffu) + lane];                                    \
    BUF[9]  = lds[(cb_.x >> 16)     + lane];                                    \
    BUF[10] = lds[(cb_.y & 0xffffu) + lane];                                    \
    BUF[11] = lds[(cb_.y >> 16)     + lane];                                    \
    BUF[12] = lds[(cb_.z & 0xffffu) + lane];                                    \
    BUF[13] = lds[(cb_.z >> 16)     + lane];                                    \
    BUF[14] = lds[(cb_.w & 0xffffu) + lane];                                    \
    BUF[15] = lds[(cb_.w >> 16)     + lane];                                    \
  } while (0)

  // Prologue: group 0 of t=0 into the LDS pipeline.
  FC1_LOADG(bf0, ct[0], ct[1]);

#define FC1_BODY(T, CT, RT) do {                                                \
    const int t_ = (T);                                                         \
    uint32_t cw_ = cnt1[bt + t_ + 1];                                           \
    PIN1(cw_);                                                                  \
    const uint4* Ln_ = Lbase + (bt + t_ + 1) * 16;                              \
    _Pragma("unroll")                                                           \
    for (int k = 0; k < 12; ++k) RT[k] = Ln_[k];                                \
    _Pragma("unroll")                                                           \
    for (int k = 0; k < 12; ++k) PIN4(RT[k]);                                   \
    const uint4* Lc_ = Lbase + (bt + t_) * 16;                                  \
    int ng_ = cntC;   /* group count, wave-uniform */                           \
    float acc = 0.f;                                                            \
    _Pragma("unroll")                                                           \
    for (int g = 0; g < 8; ++g) {                                               \
      if (g >= ng_) break;                                                      \
      if (g + 1 < ng_) {                                                        \
        uint4 cA_ = ((2*g+2) < 12) ? CT[(2*g+2) % 12] : Lc_[2*g+2];             \
        uint4 cB_ = ((2*g+3) < 12) ? CT[(2*g+3) % 12] : Lc_[2*g+3];             \
        if ((g & 1) == 0) { FC1_LOADG(bf1, cA_, cB_); }                         \
        else              { FC1_LOADG(bf0, cA_, cB_); }                         \
      }                                                                         \
      if ((g & 1) == 0) { SUM16(acc, bf0); } else { SUM16(acc, bf1); }          \
    }                                                                           \
    FC1_LOADG(bf0, RT[0], RT[1]);   /* group 0 of t+1: cross-t pipeline */      \
    cur = A_I * cur + WSC * acc;                                                \
    vol = A_V * vol + cur;                                                      \
    bool s_ = vol >= THETA;                                                     \
    vol = s_ ? 0.f : vol;                                                       \
    unsigned long long m_ = __ballot(s_);                                       \
    if (lane == 0) bits2[(bt + t_) * 16 + hq] = m_;                             \
    cntC = (int)cw_;                                                            \
  } while (0)

  for (int t = 0; t < NT - 2; t += 2) {
    FC1_BODY(t, ct, rt);
    FC1_BODY(t + 1, rt, ct);
  }
  FC1_BODY(NT - 2, ct, rt);   // t = 1022 (prefetch of t=1023 is in-bounds, unused)
#undef FC1_BODY
#undef FC1_LOADG
}

// ---------------------------------------------------------------------------
// K3: fused fc2 + LIF + both delay shifts -> final fp32 spikes.
// Same swizzle (bq lists + w2 on one XCD). 4 waves = 4 batches; lanes 0..31 /
// 32..63 take even/odd list entries for the same 32 outputs; halves combined
// via shfl_xor(32) (commutative -> bit-identical, validated). Input at tau is
// s1[tau-1]; out[p] = spike2[p-1]; 16-t register-buffered 64 B stores.
// ---------------------------------------------------------------------------
__global__ void __launch_bounds__(256, 1) k_fc2(const float* __restrict__ w2,
                                                const uint32_t* __restrict__ cnt2,
                                                const uint16_t* __restrict__ list2,
                                                float* __restrict__ out) {
  extern __shared__ float lds[];   // (NHID+1) x 32
  int xcd = blockIdx.x & 7, slot = blockIdx.x >> 3;
  int bq = (xcd << 1) | (slot & 1);
  int oq = slot >> 1;
  int o0 = oq * 32;
  for (int idx = threadIdx.x; idx < NHID * 32; idx += 256) {
    int om = idx >> 10;            // 0..31
    int i  = idx & (NHID - 1);
    lds[i * P2 + om] = w2[(size_t)(o0 + om) * NHID + i];
  }
  if (threadIdx.x < 32) lds[NHID * P2 + threadIdx.x] = 0.0f;  // sentinel row
  __syncthreads();

  int wid = threadIdx.x >> 6, lane = threadIdx.x & 63;
  int col = lane & 31;
  int sh  = (lane >> 5) << 4;      // 0 = even entries, 16 = odd entries
  int b = bq * 4 + wid;
  size_t bt = (size_t)b * NT;
  const uint4* Lbase = (const uint4*)list2;
  float* op = out + ((size_t)b * NOUT + o0 + col) * NT;

  float cur = 0.f, vol = 0.f;
  uint32_t sm = 0;
  float bf0[8], bf1[8];
  uint4 ct[8], rt[8];
#pragma unroll
  for (int k = 0; k < 8; ++k)
    ct[k] = make_uint4(0x80008000u, 0x80008000u, 0x80008000u, 0x80008000u);
  int cntC = 0;                    // tau=0 consumes zero-padded s1[-1]

#define FC2_LOADG(BUF, CA, CB) do {                                             \
    uint4 ca_ = (CA), cb_ = (CB);                                               \
    BUF[0] = lds[((ca_.x >> sh) & 0xffffu) + col];                              \
    BUF[1] = lds[((ca_.y >> sh) & 0xffffu) + col];                              \
    BUF[2] = lds[((ca_.z >> sh) & 0xffffu) + col];                              \
    BUF[3] = lds[((ca_.w >> sh) & 0xffffu) + col];                              \
    BUF[4] = lds[((cb_.x >> sh) & 0xffffu) + col];                              \
    BUF[5] = lds[((cb_.y >> sh) & 0xffffu) + col];                              \
    BUF[6] = lds[((cb_.z >> sh) & 0xffffu) + col];                              \
    BUF[7] = lds[((cb_.w >> sh) & 0xffffu) + col];                              \
  } while (0)

  FC2_LOADG(bf0, ct[0], ct[1]);    // sentinel rows, harmless (ng=0 at tau=0)

#define FC2_BODY(TAU, CT, RT) do {                                             \
    const int tau_ = (TAU);                                                     \
    uint32_t cw_ = cnt2[bt + tau_];                                             \
    PIN1(cw_);                                                                  \
    const uint4* Ln_ = Lbase + (bt + tau_) * 16;                                \
    _Pragma("unroll")                                                           \
    for (int k = 0; k < 8; ++k) RT[k] = Ln_[k];                                 \
    _Pragma("unroll")                                                           \
    for (int k = 0; k < 8; ++k) PIN4(RT[k]);                                    \
    const uint4* Lc_ = Lbase + (bt + tau_) * 16 - 16;   /* list at tau_-1 */    \
    int ng_ = cntC;                                                             \
    float acc = 0.f;                                                            \
    _Pragma("unroll")                                                           \
    for (int g = 0; g < 8; ++g) {                                               \
      if (g >= ng_) break;                                                      \
      if (g + 1 < ng_) {                                                        \
        uint4 cA_ = ((2*g+2) < 8) ? CT[(2*g+2) % 8] : Lc_[2*g+2];               \
        uint4 cB_ = ((2*g+3) < 8) ? CT[(2*g+3) % 8] : Lc_[2*g+3];               \
        if ((g & 1) == 0) { FC2_LOADG(bf1, cA_, cB_); }                         \
        else              { FC2_LOADG(bf0, cA_, cB_); }                         \
      }                                                                         \
      if ((g & 1) == 0) { SUM8(acc, bf0); } else { SUM8(acc, bf1); }            \
    }                                                                           \
    FC2_LOADG(bf0, RT[0], RT[1]);   /* group 0 of tau+1: cross-t pipeline */    \
    acc += __shfl_xor(acc, 32, 64); /* even+odd halves, commutative */          \
    cur = A_I * cur + WSC * acc;                                                \
    vol = A_V * vol + cur;                                                      \
    bool s_ = vol >= THETA;                                                     \
    vol = s_ ? 0.f : vol;                                                       \
    int p_ = tau_ + 1;                                                          \
    if (s_) sm |= (1u << (p_ & 15));                                            \
    if ((p_ & 15) == 15) {                                                      \
      if (lane < 32) {                                                          \
        float vb[16];                                                           \
        _Pragma("unroll")                                                       \
        for (int q = 0; q < 16; ++q) vb[q] = ((sm >> q) & 1u) ? 1.0f : 0.0f;    \
        float4* dst = (float4*)(op + (p_ - 15));                                \
        dst[0] = make_float4(vb[0],  vb[1],  vb[2],  vb[3]);                    \
        dst[1] = make_float4(vb[4],  vb[5],  vb[6],  vb[7]);                    \
        dst[2] = make_float4(vb[8],  vb[9],  vb[10], vb[11]);                   \
        dst[3] = make_float4(vb[12], vb[13], vb[14], vb[15]);                   \
      }                                                                         \
      sm = 0;                                                                   \
    }                                                                           \
    cntC = (int)cw_;                                                            \
  } while (0)

  for (int tau = 0; tau < NT - 2; tau += 2) {
    FC2_BODY(tau, ct, rt);
    FC2_BODY(tau + 1, rt, ct);
  }
  FC2_BODY(NT - 2, ct, rt);   // tau = 1022 -> p = 1023, final flush
#undef FC2_BODY
#undef FC2_LOADG
}

// ---------------------------------------------------------------------------
// ws layout (bytes): bits1 u32[64K*16] @0 (4MB); cnt1 @4194304 (256KB);
// list1 u16[64K*128] @4456448 (16MB); bits2 u64[64K*16] @21233664 (8MB);
// cnt2 @29622272 (256KB); list2 @29884416 (16MB).
// ---------------------------------------------------------------------------
extern "C" void kernel_launch(void* const* d_in, const int* in_sizes, int n_in,
                              void* d_out, int out_size, void* d_ws, size_t ws_size,
                              hipStream_t stream) {
  const float* x  = (const float*)d_in[0];
  const float* w1 = (const float*)d_in[1];
  const float* w2 = (const float*)d_in[2];
  float* out = (float*)d_out;

  char* ws = (char*)d_ws;
  uint32_t* bits1 = (uint32_t*)(ws);
  uint32_t* cnt1  = (uint32_t*)(ws + 4194304);
  uint16_t* list1 = (uint16_t*)(ws + 4456448);
  uint64_t* bits2 = (uint64_t*)(ws + 21233664);
  uint32_t* cnt2  = (uint32_t*)(ws + 29622272);
  uint16_t* list2 = (uint16_t*)(ws + 29884416);

  const int LDS1 = (NIN + 1) * P1 * 4;    // 131328
  const int LDS2 = (NHID + 1) * P2 * 4;   // 131200
  (void)hipFuncSetAttribute((const void*)k_fc1,
      hipFuncAttributeMaxDynamicSharedMemorySize, LDS1);
  (void)hipFuncSetAttribute((const void*)k_fc2,
      hipFuncAttributeMaxDynamicSharedMemorySize, LDS2);

  k_bits1 <<<NB * 16 * 4, 256, 0, stream>>>(x, bits1);
  k_extract<<<(NB * NT) / 256, 256, 0, stream>>>((const uint64_t*)bits1, cnt1,
                                                 list1, 8, NIN << 6, 6);
  k_fc1   <<<16 * 16, 256, LDS1, stream>>>(w1, cnt1, list1, bits2);
  k_extract<<<(NB * NT) / 256, 256, 0, stream>>>(bits2, cnt2, list2, 16,
                                                 NHID << 5, 5);
  k_fc2   <<<16 * 16, 256, LDS2, stream>>>(w2, cnt2, list2, out);
}

// Round 5
// 1433.205 us; speedup vs baseline: 1.3203x; 1.3203x over previous
//
#include <hip/hip_runtime.h>
#include <stdint.h>

// Problem sizes (fixed by reference)
#define NB   64
#define NIN  512
#define NHID 1024
#define NOUT 512
#define NT   1024

#define LSTRIDE 128   // u16 entries per (b,t) list, sentinel-padded to FULL length
#define P1 64         // fc1 tile dword pitch
#define P2 32         // fc2 tile dword pitch

// Loihi CUBA constants (exact in fp32)
#define A_I   0.75f
#define A_V   0.96875f
#define WSC   64.0f
#define THETA 5120.0f

typedef uint32_t u32x4 __attribute__((ext_vector_type(4)));

// Un-sinkable prefetch: a real global_load issued HERE. The matching
// s_waitcnt asm at the end of the body takes the destination registers as
// "+v" operands, so every later use is data-ordered after the wait, and
// volatile<->volatile ordering keeps the loads at the issue point.
#define GL4(DST, PTR, OFF) \
  asm volatile("global_load_dwordx4 %0, %1, off offset:" OFF : "=v"(DST) : "v"(PTR))
#define GL1(DST, PTR) \
  asm volatile("global_load_dword %0, %1, off" : "=v"(DST) : "v"(PTR))

#define PREFETCH16(RT, LP, CW, CP) do {                                         \
    GL1(CW, CP);                                                                \
    GL4(RT[0],  LP, "0");   GL4(RT[1],  LP, "16");                              \
    GL4(RT[2],  LP, "32");  GL4(RT[3],  LP, "48");                              \
    GL4(RT[4],  LP, "64");  GL4(RT[5],  LP, "80");                              \
    GL4(RT[6],  LP, "96");  GL4(RT[7],  LP, "112");                             \
    GL4(RT[8],  LP, "128"); GL4(RT[9],  LP, "144");                             \
    GL4(RT[10], LP, "160"); GL4(RT[11], LP, "176");                             \
    GL4(RT[12], LP, "192"); GL4(RT[13], LP, "208");                             \
    GL4(RT[14], LP, "224"); GL4(RT[15], LP, "240");                             \
  } while (0)

#define WAITJOIN16(RT, CW)                                                      \
    asm volatile("s_waitcnt vmcnt(0)"                                           \
      : "+v"(RT[0]),  "+v"(RT[1]),  "+v"(RT[2]),  "+v"(RT[3]),                  \
        "+v"(RT[4]),  "+v"(RT[5]),  "+v"(RT[6]),  "+v"(RT[7]),                  \
        "+v"(RT[8]),  "+v"(RT[9]),  "+v"(RT[10]), "+v"(RT[11]),                 \
        "+v"(RT[12]), "+v"(RT[13]), "+v"(RT[14]), "+v"(RT[15]), "+v"(CW)        \
      :: "memory")

// ---------------------------------------------------------------------------
// K1: binarize x (B,Nin,T) fp32 -> bitmask bits1[b][t][iw] (u32), coalesced.
// ---------------------------------------------------------------------------
__global__ void __launch_bounds__(256) k_bits1(const float* __restrict__ x,
                                               uint32_t* __restrict__ bits1) {
  int blk = blockIdx.x;          // b*64 + iw*4 + tc
  int b  = blk >> 6;
  int iw = (blk >> 2) & 15;
  int tc = blk & 3;
  int t  = tc * 256 + threadIdx.x;
  const float* xp = x + ((size_t)(b * NIN + iw * 32)) * NT + t;
  uint32_t w = 0;
#pragma unroll
  for (int j = 0; j < 32; ++j) {
    float v = xp[(size_t)j * NT];
    if (v > 0.5f) w |= (1u << j);
  }
  bits1[((size_t)b * NT + t) * 16 + iw] = w;
}

// ---------------------------------------------------------------------------
// Extract per-(b,t) ascending index lists, PRE-SCALED by <<shift (consumer's
// LDS dword index = val + lane). cnt stores the GROUP count ceil(c/16). Full
// LSTRIDE sentinel-padded (sentinel maps to the zeroed LDS row; +0.0f adds
// are bit-neutral).
// ---------------------------------------------------------------------------
__global__ void __launch_bounds__(256) k_extract(const uint64_t* __restrict__ bits,
                                                 uint32_t* __restrict__ cnt,
                                                 uint16_t* __restrict__ list,
                                                 int words, int sentinel_scaled,
                                                 int shift) {
  int gid = blockIdx.x * 256 + threadIdx.x;   // = b*NT + t
  const uint64_t* wp = bits + (size_t)gid * words;
  uint16_t* lp = list + (size_t)gid * LSTRIDE;
  int c = 0;
  for (int w = 0; w < words; ++w) {
    uint64_t v = wp[w];
    while (v) {
      int j = __builtin_ctzll(v);
      v &= v - 1;
      if (c < LSTRIDE) lp[c] = (uint16_t)(((w << 6) + j) << shift);
      ++c;
    }
  }
  if (c > LSTRIDE) c = LSTRIDE;
  cnt[gid] = (uint32_t)((c + 15) >> 4);       // group count
  int cp = c;
  if (cp & 1) { lp[cp] = (uint16_t)sentinel_scaled; ++cp; }
  uint32_t s2 = (uint32_t)sentinel_scaled * 0x10001u;
  uint32_t* lp32 = (uint32_t*)lp;
  for (int k = cp >> 1; k < LSTRIDE / 2; ++k) lp32[k] = s2;
}

// Sequential single-accumulator sums: order = ascending list entries,
// bit-identical to the validated round-1/3/4 kernels.
#define SUM16(ACC, B) do { _Pragma("unroll") \
  for (int q_ = 0; q_ < 16; ++q_) (ACC) += (B)[q_]; } while (0)
#define SUM8(ACC, B) do { _Pragma("unroll") \
  for (int q_ = 0; q_ < 8; ++q_) (ACC) += (B)[q_]; } while (0)

// ---------------------------------------------------------------------------
// K2: fused fc1 + LIF -> spike bitmask bits2[b][t][hq] (u64).
// XCD-swizzled blocks (lists + w1 of one bq resident in one XCD's L2).
// 4 waves = 4 batches, 64 lanes = 64 hidden. Whole next-t list (16 uint4 =
// 128 entries = the validated truncation bound, no fallback path) prefetched
// via inline-asm global loads, joined by a counted s_waitcnt at body end.
// 16-entry ping-pong LDS pipeline carried across t boundaries.
// ---------------------------------------------------------------------------
__global__ void __launch_bounds__(256, 1) k_fc1(const float* __restrict__ w1,
                                                const uint32_t* __restrict__ cnt1,
                                                const uint16_t* __restrict__ list1,
                                                uint64_t* __restrict__ bits2) {
  extern __shared__ float lds[];   // (NIN+1) x 64
  int xcd = blockIdx.x & 7, slot = blockIdx.x >> 3;
  int bq = (xcd << 1) | (slot & 1);
  int hq = slot >> 1;
  int h0 = hq * 64;
  for (int idx = threadIdx.x; idx < NIN * 64; idx += 256) {
    int hl = idx >> 9;             // 0..63
    int i  = idx & (NIN - 1);
    lds[i * P1 + hl] = w1[(size_t)(h0 + hl) * NIN + i];
  }
  if (threadIdx.x < 64) lds[NIN * P1 + threadIdx.x] = 0.0f;  // sentinel row
  __syncthreads();

  int wid = threadIdx.x >> 6, lane = threadIdx.x & 63;
  int b = bq * 4 + wid;
  size_t bt = (size_t)b * NT;
  float cur = 0.f, vol = 0.f;
  float bf0[16], bf1[16];
  u32x4 ct[16], rt[16];
  int cntC;
  {
    const u32x4* Lp = (const u32x4*)(list1 + bt * LSTRIDE);
#pragma unroll
    for (int k = 0; k < 16; ++k) ct[k] = Lp[k];
    cntC = (int)cnt1[bt];
  }

#define FC1_LOADG(BUF, CA, CB) do {                                             \
    u32x4 ca_ = (CA), cb_ = (CB);                                               \
    BUF[0]  = lds[(ca_[0] & 0xffffu) + lane];                                   \
    BUF[1]  = lds[(ca_[0] >> 16)     + lane];                                   \
    BUF[2]  = lds[(ca_[1] & 0xffffu) + lane];                                   \
    BUF[3]  = lds[(ca_[1] >> 16)     + lane];                                   \
    BUF[4]  = lds[(ca_[2] & 0xffffu) + lane];                                   \
    BUF[5]  = lds[(ca_[2] >> 16)     + lane];                                   \
    BUF[6]  = lds[(ca_[3] & 0xffffu) + lane];                                   \
    BUF[7]  = lds[(ca_[3] >> 16)     + lane];                                   \
    BUF[8]  = lds[(cb_[0] & 0xffffu) + lane];                                   \
    BUF[9]  = lds[(cb_[0] >> 16)     + lane];                                   \
    BUF[10] = lds[(cb_[1] & 0xffffu) + lane];                                   \
    BUF[11] = lds[(cb_[1] >> 16)     + lane];                                   \
    BUF[12] = lds[(cb_[2] & 0xffffu) + lane];                                   \
    BUF[13] = lds[(cb_[2] >> 16)     + lane];                                   \
    BUF[14] = lds[(cb_[3] & 0xffffu) + lane];                                   \
    BUF[15] = lds[(cb_[3] >> 16)     + lane];                                   \
  } while (0)

  // Prologue: group 0 of t=0 into the LDS ping-pong pipeline.
  FC1_LOADG(bf0, ct[0], ct[1]);

#define FC1_BODY(T, CT, RT) do {                                                \
    const int t_ = (T);                                                         \
    const uint16_t* lp_ = list1 + (bt + t_ + 1) * LSTRIDE;                      \
    const uint32_t* cp_ = cnt1 + (bt + t_ + 1);                                 \
    uint32_t cw_;                                                               \
    PREFETCH16(RT, lp_, cw_, cp_);                                              \
    int ng_ = __builtin_amdgcn_readfirstlane(cntC);                             \
    float acc = 0.f;                                                            \
    _Pragma("unroll")                                                           \
    for (int g = 0; g < 8; ++g) {                                               \
      if (g >= ng_) break;                                                      \
      if (g + 1 < 8 && g + 1 < ng_) {                                           \
        if ((g & 1) == 0) { FC1_LOADG(bf1, CT[2*g+2], CT[2*g+3]); }             \
        else              { FC1_LOADG(bf0, CT[2*g+2], CT[2*g+3]); }             \
      }                                                                         \
      if ((g & 1) == 0) { SUM16(acc, bf0); } else { SUM16(acc, bf1); }          \
    }                                                                           \
    WAITJOIN16(RT, cw_);                                                        \
    FC1_LOADG(bf0, RT[0], RT[1]);   /* group 0 of t+1: cross-t pipeline */      \
    cur = A_I * cur + WSC * acc;                                                \
    vol = A_V * vol + cur;                                                      \
    bool s_ = vol >= THETA;                                                     \
    vol = s_ ? 0.f : vol;                                                       \
    unsigned long long m_ = __ballot(s_);                                       \
    if (lane == 0) bits2[(bt + t_) * 16 + hq] = m_;                             \
    cntC = (int)cw_;                                                            \
  } while (0)

  for (int t = 0; t < NT - 2; t += 2) {
    FC1_BODY(t, ct, rt);
    FC1_BODY(t + 1, rt, ct);
  }
  FC1_BODY(NT - 2, ct, rt);   // t = 1022 (prefetch of t=1023 is in-bounds, unused)
#undef FC1_BODY
#undef FC1_LOADG
}

// ---------------------------------------------------------------------------
// K3: fused fc2 + LIF + both delay shifts -> final fp32 spikes.
// Same swizzle. 4 waves = 4 batches; lanes 0..31 / 32..63 take even/odd list
// entries for the same 32 outputs; halves combined via shfl_xor(32)
// (commutative -> bit-identical, validated). Input at tau is s1[tau-1];
// out[p] = spike2[p-1]; 16-t register-buffered 64 B stores.
// ---------------------------------------------------------------------------
__global__ void __launch_bounds__(256, 1) k_fc2(const float* __restrict__ w2,
                                                const uint32_t* __restrict__ cnt2,
                                                const uint16_t* __restrict__ list2,
                                                float* __restrict__ out) {
  extern __shared__ float lds[];   // (NHID+1) x 32
  int xcd = blockIdx.x & 7, slot = blockIdx.x >> 3;
  int bq = (xcd << 1) | (slot & 1);
  int oq = slot >> 1;
  int o0 = oq * 32;
  for (int idx = threadIdx.x; idx < NHID * 32; idx += 256) {
    int om = idx >> 10;            // 0..31
    int i  = idx & (NHID - 1);
    lds[i * P2 + om] = w2[(size_t)(o0 + om) * NHID + i];
  }
  if (threadIdx.x < 32) lds[NHID * P2 + threadIdx.x] = 0.0f;  // sentinel row
  __syncthreads();

  int wid = threadIdx.x >> 6, lane = threadIdx.x & 63;
  int col = lane & 31;
  int sh  = (lane >> 5) << 4;      // 0 = even entries, 16 = odd entries
  int b = bq * 4 + wid;
  size_t bt = (size_t)b * NT;
  float* op = out + ((size_t)b * NOUT + o0 + col) * NT;

  float cur = 0.f, vol = 0.f;
  uint32_t sm = 0;
  float bf0[8], bf1[8];
  u32x4 ct[16], rt[16];
#pragma unroll
  for (int k = 0; k < 16; ++k)
    ct[k] = (u32x4){0x80008000u, 0x80008000u, 0x80008000u, 0x80008000u};
  int cntC = 0;                    // tau=0 consumes zero-padded s1[-1]

#define FC2_LOADG(BUF, CA, CB) do {                                             \
    u32x4 ca_ = (CA), cb_ = (CB);                                               \
    BUF[0] = lds[((ca_[0] >> sh) & 0xffffu) + col];                             \
    BUF[1] = lds[((ca_[1] >> sh) & 0xffffu) + col];                             \
    BUF[2] = lds[((ca_[2] >> sh) & 0xffffu) + col];                             \
    BUF[3] = lds[((ca_[3] >> sh) & 0xffffu) + col];                             \
    BUF[4] = lds[((cb_[0] >> sh) & 0xffffu) + col];                             \
    BUF[5] = lds[((cb_[1] >> sh) & 0xffffu) + col];                             \
    BUF[6] = lds[((cb_[2] >> sh) & 0xffffu) + col];                             \
    BUF[7] = lds[((cb_[3] >> sh) & 0xffffu) + col];                             \
  } while (0)

  FC2_LOADG(bf0, ct[0], ct[1]);    // sentinel rows, harmless (ng=0 at tau=0)

#define FC2_BODY(TAU, CT, RT) do {                                             \
    const int tau_ = (TAU);                                                     \
    const uint16_t* lp_ = list2 + (bt + tau_) * LSTRIDE;                        \
    const uint32_t* cp_ = cnt2 + (bt + tau_);                                   \
    uint32_t cw_;                                                               \
    PREFETCH16(RT, lp_, cw_, cp_);                                              \
    int ng_ = __builtin_amdgcn_readfirstlane(cntC);                             \
    float acc = 0.f;                                                            \
    _Pragma("unroll")                                                           \
    for (int g = 0; g < 8; ++g) {                                               \
      if (g >= ng_) break;                                                      \
      if (g + 1 < 8 && g + 1 < ng_) {                                           \
        if ((g & 1) == 0) { FC2_LOADG(bf1, CT[2*g+2], CT[2*g+3]); }             \
        else              { FC2_LOADG(bf0, CT[2*g+2], CT[2*g+3]); }             \
      }                                                                         \
      if ((g & 1) == 0) { SUM8(acc, bf0); } else { SUM8(acc, bf1); }            \
    }                                                                           \
    WAITJOIN16(RT, cw_);                                                        \
    FC2_LOADG(bf0, RT[0], RT[1]);   /* group 0 of tau+1: cross-t pipeline */    \
    acc += __shfl_xor(acc, 32, 64); /* even+odd halves, commutative */          \
    cur = A_I * cur + WSC * acc;                                                \
    vol = A_V * vol + cur;                                                      \
    bool s_ = vol >= THETA;                                                     \
    vol = s_ ? 0.f : vol;                                                       \
    int p_ = tau_ + 1;                                                          \
    if (s_) sm |= (1u << (p_ & 15));                                            \
    if ((p_ & 15) == 15) {                                                      \
      if (lane < 32) {                                                          \
        float vb[16];                                                           \
        _Pragma("unroll")                                                       \
        for (int q = 0; q < 16; ++q) vb[q] = ((sm >> q) & 1u) ? 1.0f : 0.0f;    \
        float4* dst = (float4*)(op + (p_ - 15));                                \
        dst[0] = make_float4(vb[0],  vb[1],  vb[2],  vb[3]);                    \
        dst[1] = make_float4(vb[4],  vb[5],  vb[6],  vb[7]);                    \
        dst[2] = make_float4(vb[8],  vb[9],  vb[10], vb[11]);                   \
        dst[3] = make_float4(vb[12], vb[13], vb[14], vb[15]);                   \
      }                                                                         \
      sm = 0;                                                                   \
    }                                                                           \
    cntC = (int)cw_;                                                            \
  } while (0)

  for (int tau = 0; tau < NT - 2; tau += 2) {
    FC2_BODY(tau, ct, rt);
    FC2_BODY(tau + 1, rt, ct);
  }
  FC2_BODY(NT - 2, ct, rt);   // tau = 1022 -> p = 1023, final flush
#undef FC2_BODY
#undef FC2_LOADG
}

// ---------------------------------------------------------------------------
// ws layout (bytes): bits1 u32[64K*16] @0 (4MB); cnt1 @4194304 (256KB);
// list1 u16[64K*128] @4456448 (16MB); bits2 u64[64K*16] @21233664 (8MB);
// cnt2 @29622272 (256KB); list2 @29884416 (16MB).
// ---------------------------------------------------------------------------
extern "C" void kernel_launch(void* const* d_in, const int* in_sizes, int n_in,
                              void* d_out, int out_size, void* d_ws, size_t ws_size,
                              hipStream_t stream) {
  const float* x  = (const float*)d_in[0];
  const float* w1 = (const float*)d_in[1];
  const float* w2 = (const float*)d_in[2];
  float* out = (float*)d_out;

  char* ws = (char*)d_ws;
  uint32_t* bits1 = (uint32_t*)(ws);
  uint32_t* cnt1  = (uint32_t*)(ws + 4194304);
  uint16_t* list1 = (uint16_t*)(ws + 4456448);
  uint64_t* bits2 = (uint64_t*)(ws + 21233664);
  uint32_t* cnt2  = (uint32_t*)(ws + 29622272);
  uint16_t* list2 = (uint16_t*)(ws + 29884416);

  const int LDS1 = (NIN + 1) * P1 * 4;    // 131328
  const int LDS2 = (NHID + 1) * P2 * 4;   // 131200
  (void)hipFuncSetAttribute((const void*)k_fc1,
      hipFuncAttributeMaxDynamicSharedMemorySize, LDS1);
  (void)hipFuncSetAttribute((const void*)k_fc2,
      hipFuncAttributeMaxDynamicSharedMemorySize, LDS2);

  k_bits1 <<<NB * 16 * 4, 256, 0, stream>>>(x, bits1);
  k_extract<<<(NB * NT) / 256, 256, 0, stream>>>((const uint64_t*)bits1, cnt1,
                                                 list1, 8, NIN << 6, 6);
  k_fc1   <<<16 * 16, 256, LDS1, stream>>>(w1, cnt1, list1, bits2);
  k_extract<<<(NB * NT) / 256, 256, 0, stream>>>(bits2, cnt2, list2, 16,
                                                 NHID << 5, 5);
  k_fc2   <<<16 * 16, 256, LDS2, stream>>>(w2, cnt2, list2, out);
}